// Round 10
// baseline (120.636 us; speedup 1.0000x reference)
//
#include <hip/hip_runtime.h>
#include <stdint.h>

#define B_   32
#define CIN  128
#define HH   56
#define WW   56
#define COUT 256
#define QDIV 7.5f

#define NBLK_AX 2048
#define NBLK_AW 288
#define NBLK_QX (B_ * HH)   // 1792
#define NBLK_QW 288

#define NSLOT 58
#define CSTRIDE (NSLOT * 16)       // 928 B per ci-chunk
#define ROWB (8 * CSTRIDE)         // 7424 B per image row
#define WGRP 73728                 // 72 KB weights per 64-co group (36 chunks * 2 KB)

typedef int v4i  __attribute__((ext_vector_type(4)));
typedef int v16i __attribute__((ext_vector_type(16)));

typedef __attribute__((address_space(3))) unsigned char lds_u8;
typedef __attribute__((address_space(1))) const unsigned char glb_u8;

__device__ __forceinline__ void load_lds16(const void* g, void* l) {
    __builtin_amdgcn_global_load_lds((glb_u8*)g, (lds_u8*)l, 16, 0, 0);
}

// ---------- absmax: blocks [0,2048) -> x, [2048,2336) -> w ----------
__global__ __launch_bounds__(256) void absmax_all_kernel(const float* __restrict__ x,
                                                         const float* __restrict__ w,
                                                         unsigned* __restrict__ mbits) {
    const float* p; int n4, i, stride; unsigned* slot;
    if (blockIdx.x < NBLK_AX) {
        p = x; n4 = B_ * CIN * HH * WW / 4;
        i = blockIdx.x * 256 + threadIdx.x; stride = NBLK_AX * 256; slot = mbits;
    } else {
        p = w; n4 = COUT * CIN * 9 / 4;
        i = (blockIdx.x - NBLK_AX) * 256 + threadIdx.x; stride = NBLK_AW * 256; slot = mbits + 1;
    }
    float m = 0.f;
    for (; i < n4; i += stride) {
        float4 v = ((const float4*)p)[i];
        m = fmaxf(m, fmaxf(fmaxf(fabsf(v.x), fabsf(v.y)),
                           fmaxf(fabsf(v.z), fabsf(v.w))));
    }
    #pragma unroll
    for (int off = 32; off; off >>= 1) m = fmaxf(m, __shfl_down(m, off));
    __shared__ float red[4];
    int lane = threadIdx.x & 63, wv = threadIdx.x >> 6;
    if (lane == 0) red[wv] = m;
    __syncthreads();
    if (threadIdx.x == 0) {
        m = fmaxf(fmaxf(red[0], red[1]), fmaxf(red[2], red[3]));
        atomicMax(slot, __float_as_uint(m));
    }
}

// ---------- quantize: blocks [0,1792) -> x, [1792,2080) -> w ----------
// qx: per (b,h) row of 7424 B: byte = c*928 + s*16 + j; slot s in [1,56] holds
//     pixel w = s-1, ci = c*16+j; slots 0 and 57 zero.
// qw3: byte = g*73728 + k*2048 + mi*1024 + jh*512 + co31*16 + jl
//   co = g*64 + mi*32 + co31, k = (kh*3+kw)*4 + cc, ci = cc*32 + jh*16 + jl.
__global__ __launch_bounds__(256) void quant_all_kernel(const float* __restrict__ x,
                                                        const float* __restrict__ w,
                                                        signed char* __restrict__ qx,
                                                        int* __restrict__ qw,
                                                        const unsigned* __restrict__ mbits) {
    if (blockIdx.x < NBLK_QX) {
        __shared__ signed char tile[WW * 132];
        const int bh = blockIdx.x;
        const int b = bh / HH, h = bh % HH;
        const float s = __uint_as_float(mbits[0]) / QDIV;
        const float* src = x + (size_t)b * (CIN * HH * WW) + (size_t)h * WW;
        #pragma unroll
        for (int i = 0; i < 7; ++i) {                 // 128 ci * 14 float4 = 1792
            int e = threadIdx.x + i * 256;
            int ci = e / 14, wq = e - ci * 14;
            float4 v = *(const float4*)(src + (size_t)ci * (HH * WW) + wq * 4);
            float qa = fminf(fmaxf(rintf(v.x / s), -8.f), 7.f);
            float qb = fminf(fmaxf(rintf(v.y / s), -8.f), 7.f);
            float qc = fminf(fmaxf(rintf(v.z / s), -8.f), 7.f);
            float qd = fminf(fmaxf(rintf(v.w / s), -8.f), 7.f);
            signed char* tp = &tile[(wq * 4) * 132 + ci];
            tp[0]   = (signed char)qa;
            tp[132] = (signed char)qb;
            tp[264] = (signed char)qc;
            tp[396] = (signed char)qd;
        }
        __syncthreads();
        int* dst = (int*)(qx + (size_t)bh * ROWB);
        for (int d = threadIdx.x; d < ROWB / 4; d += 256) {   // 1856 dwords
            int u = d >> 2, dw = d & 3;
            int c = u / NSLOT, s2 = u - c * NSLOT;
            int v = 0;
            if (s2 >= 1 && s2 <= WW)
                v = *(const int*)&tile[(s2 - 1) * 132 + c * 16 + dw * 4];
            dst[d] = v;
        }
    } else {
        int d = (blockIdx.x - NBLK_QX) * 256 + threadIdx.x;  // 73728 dwords
        int g  = d / 18432;
        int r1 = d - g * 18432;
        int k  = r1 >> 9;
        int q9 = r1 & 511;
        int mi = q9 >> 8;
        int u2 = q9 & 255;
        int jh = u2 >> 7;
        int co31 = (u2 >> 2) & 31;
        int jl4  = u2 & 3;
        int co = g * 64 + mi * 32 + co31;
        int t = k >> 2, cc = k & 3;
        int kh = t / 3, kw = t - kh * 3;
        float s = __uint_as_float(mbits[1]) / QDIV;
        int pack = 0;
        #pragma unroll
        for (int j = 0; j < 4; ++j) {
            int ci = cc * 32 + jh * 16 + jl4 * 4 + j;
            float v = w[(((size_t)co * CIN + ci) * 3 + kh) * 3 + kw];
            float q = fminf(fmaxf(rintf(v / s), -8.f), 7.f);
            pack |= (((int)q) & 0xFF) << (8 * j);
        }
        qw[d] = pack;
    }
}

// ---------- conv: i8-MFMA; weights in LDS (once), x streamed L2->regs ----------
// Block: 256 thr / 4 waves; 64 co (group g) x 4 output rows; wave = 64co x 56px,
// acc[2][2]. LDS = all 36 weight chunks (72 KB) -> 2 blocks/CU. K-loop has ZERO
// barriers and ZERO LDS traffic for x: B-fragments are coalesced per-lane global
// loads from L2-resident qx (depth-2 explicit prefetch); A from LDS lane-linear.
__global__ __launch_bounds__(256, 2) void conv_mfma_kernel(
        const signed char* __restrict__ qxz,   // base of [zero row | qx rows]
        const signed char* __restrict__ qw3,
        const unsigned* __restrict__ mbits,
        const float* __restrict__ bias,
        float* __restrict__ out) {
    __shared__ signed char wlds[WGRP];

    // XCD-chunked swizzle (1792 % 8 == 0 -> bijective); g fastest in a chunk
    const int sbid = (blockIdx.x & 7) * 224 + (blockIdx.x >> 3);
    const int g    = sbid & 3;
    const int brg  = sbid >> 2;       // 0..447
    const int rg   = brg % 14;
    const int b    = brg / 14;
    const int h0   = rg * 4;

    const int tid    = threadIdx.x;
    const int rowidx = tid >> 6;      // wave id = output row 0..3
    const int lane   = tid & 63;
    const int l31    = tid & 31;
    const int lhalf  = (tid >> 5) & 1;

    // ---- stage all 36 weight chunks once (4608 x 16B), then no barriers ----
    const signed char* wgrp = qw3 + (size_t)g * WGRP;
    #pragma unroll
    for (int i = 0; i < 18; ++i)
        load_lds16(wgrp + (tid + i * 256) * 16, wlds + (tid + i * 256) * 16);
    __syncthreads();

    // per-wave row base offsets into qxz (0 = the zero row); wave-uniform SGPRs
    const int hybase = h0 + rowidx - 1;
    int ro0 = (hybase >= 0) ? (1 + b * HH + hybase) * ROWB : 0;
    int ro1 = (1 + b * HH + hybase + 1) * ROWB;
    int ro2 = (hybase + 2 < HH) ? (1 + b * HH + hybase + 2) * ROWB : 0;
    ro0 = __builtin_amdgcn_readfirstlane(ro0);
    ro1 = __builtin_amdgcn_readfirstlane(ro1);
    ro2 = __builtin_amdgcn_readfirstlane(ro2);
    const signed char* rp0 = qxz + ro0;
    const signed char* rp1 = qxz + ro1;
    const signed char* rp2 = qxz + ro2;
    const int lane_off = lhalf * CSTRIDE + l31 * 16;

    v16i acc[2][2];
    #pragma unroll
    for (int mi = 0; mi < 2; ++mi)
        #pragma unroll
        for (int ni = 0; ni < 2; ++ni)
            #pragma unroll
            for (int r = 0; r < 16; ++r) acc[mi][ni][r] = 0;

    v4i pb0[2], pb1[2];
#define BLOAD(K, SL)                                                               \
    {                                                                              \
        const int t_ = (K) >> 2, cc_ = (K) & 3;                                    \
        const int kh_ = t_ / 3, kw_ = t_ - kh_ * 3;                                \
        const signed char* rp_ = (kh_ == 0) ? rp0 : ((kh_ == 1) ? rp1 : rp2);      \
        const signed char* bp_ = rp_ + cc_ * (2 * CSTRIDE) + kw_ * 16 + lane_off;  \
        pb0[SL] = *(const v4i*)bp_;                                                \
        pb1[SL] = *(const v4i*)(bp_ + 512);                                        \
    }

    BLOAD(0, 0)
    BLOAD(1, 1)

    #pragma unroll
    for (int k = 0; k < 36; ++k) {
        const v4i b0 = pb0[k & 1];
        const v4i b1 = pb1[k & 1];
        if (k + 2 < 36) BLOAD(k + 2, k & 1)
        const signed char* ap = wlds + k * 2048 + lane * 16;
        const v4i a0 = *(const v4i*)ap;
        const v4i a1 = *(const v4i*)(ap + 1024);
        acc[0][0] = __builtin_amdgcn_mfma_i32_32x32x32_i8(a0, b0, acc[0][0], 0, 0, 0);
        acc[1][0] = __builtin_amdgcn_mfma_i32_32x32x32_i8(a1, b0, acc[1][0], 0, 0, 0);
        acc[0][1] = __builtin_amdgcn_mfma_i32_32x32x32_i8(a0, b1, acc[0][1], 0, 0, 0);
        acc[1][1] = __builtin_amdgcn_mfma_i32_32x32x32_i8(a1, b1, acc[1][1], 0, 0, 0);
    }
#undef BLOAD

    // ---- epilogue: dequant + bias ----
    const float s = (__uint_as_float(mbits[0]) / QDIV) *
                    (__uint_as_float(mbits[1]) / QDIV);
    const int hrow = h0 + rowidx;
    #pragma unroll
    for (int mi = 0; mi < 2; ++mi) {
        #pragma unroll
        for (int r = 0; r < 16; ++r) {
            const int co = g * 64 + mi * 32 + (r & 3) + 8 * (r >> 2) + 4 * lhalf;
            const float bv = bias[co];
            float* orow = out + ((size_t)(b * COUT + co) * HH + hrow) * WW;
            orow[l31] = (float)acc[mi][0][r] * s + bv;
            if (l31 < WW - 32) orow[32 + l31] = (float)acc[mi][1][r] * s + bv;
        }
    }
}

extern "C" void kernel_launch(void* const* d_in, const int* in_sizes, int n_in,
                              void* d_out, int out_size, void* d_ws, size_t ws_size,
                              hipStream_t stream) {
    const float* x    = (const float*)d_in[0];
    const float* w    = (const float*)d_in[1];
    const float* bias = (const float*)d_in[2];
    float* out = (float*)d_out;

    unsigned* mbits = (unsigned*)d_ws;
    signed char* qxz = (signed char*)d_ws + 256;     // [zero row | qx rows]
    signed char* qx  = qxz + ROWB;
    signed char* qw3 = qx + (size_t)B_ * HH * ROWB;

    hipMemsetAsync(d_ws, 0, 256 + ROWB, stream);     // mbits + zero row
    hipLaunchKernelGGL(absmax_all_kernel, dim3(NBLK_AX + NBLK_AW), dim3(256), 0, stream,
                       x, w, mbits);
    hipLaunchKernelGGL(quant_all_kernel, dim3(NBLK_QX + NBLK_QW), dim3(256), 0, stream,
                       x, w, qx, (int*)qw3, mbits);
    hipLaunchKernelGGL(conv_mfma_kernel, dim3(B_ * 14 * 4), dim3(256), 0, stream,
                       qxz, qw3, mbits, bias, out);
}

// Round 11
// 106.611 us; speedup vs baseline: 1.1316x; 1.1316x over previous
//
#include <hip/hip_runtime.h>
#include <stdint.h>

#define B_   32
#define CIN  128
#define HH   56
#define WW   56
#define COUT 256
#define QDIV 7.5f

#define NBLK_AX 2048
#define NBLK_AW 288
#define NBLK_QX (B_ * HH)   // 1792
#define NBLK_QW 288

#define NSLOT 66
#define CSTRIDE (NSLOT * 16)       // 1056 B per ci-chunk
#define ROWB (8 * CSTRIDE)         // 8448 B per image row
#define XLDS (4 * ROWB)            // 33792 (rows h0-1..h0+2)
#define WCHUNK 8192                // one k-chunk: 256 co x 32 ci
#define LDS_TOTAL (XLDS + 4 * WCHUNK)  // 66560 -> 2 blocks/CU

typedef int v4i  __attribute__((ext_vector_type(4)));
typedef int v16i __attribute__((ext_vector_type(16)));

typedef __attribute__((address_space(3))) unsigned char lds_u8;
typedef __attribute__((address_space(1))) const unsigned char glb_u8;

__device__ __forceinline__ void load_lds16(const void* g, void* l) {
    __builtin_amdgcn_global_load_lds((glb_u8*)g, (lds_u8*)l, 16, 0, 0);
}

// ---------- absmax: blocks [0,2048) -> x, [2048,2336) -> w ----------
__global__ __launch_bounds__(256) void absmax_all_kernel(const float* __restrict__ x,
                                                         const float* __restrict__ w,
                                                         unsigned* __restrict__ mbits) {
    const float* p; int n4, i, stride; unsigned* slot;
    if (blockIdx.x < NBLK_AX) {
        p = x; n4 = B_ * CIN * HH * WW / 4;
        i = blockIdx.x * 256 + threadIdx.x; stride = NBLK_AX * 256; slot = mbits;
    } else {
        p = w; n4 = COUT * CIN * 9 / 4;
        i = (blockIdx.x - NBLK_AX) * 256 + threadIdx.x; stride = NBLK_AW * 256; slot = mbits + 1;
    }
    float m = 0.f;
    for (; i < n4; i += stride) {
        float4 v = ((const float4*)p)[i];
        m = fmaxf(m, fmaxf(fmaxf(fabsf(v.x), fabsf(v.y)),
                           fmaxf(fabsf(v.z), fabsf(v.w))));
    }
    #pragma unroll
    for (int off = 32; off; off >>= 1) m = fmaxf(m, __shfl_down(m, off));
    __shared__ float red[4];
    int lane = threadIdx.x & 63, wv = threadIdx.x >> 6;
    if (lane == 0) red[wv] = m;
    __syncthreads();
    if (threadIdx.x == 0) {
        m = fmaxf(fmaxf(red[0], red[1]), fmaxf(red[2], red[3]));
        atomicMax(slot, __float_as_uint(m));
    }
}

// ---------- quantize: blocks [0,1792) -> x, [1792,2080) -> w ----------
// qx: per (b,h) row of 8448 B: byte = c*1056 + s*16 + j; slot s in [1,56] holds
//     pixel w = s-1, ci = c*16+j; slots 0 and 57..65 zero.
// qw3 (chunk-major): byte = k*8192 + wrh*4096 + mi*1024 + jh*512 + co31*16 + jl
//   co = wrh*128 + mi*32 + co31, k = (kh*3+kw)*4 + cc, ci = cc*32 + jh*16 + jl.
//   A-frag(k, wrh, mi) = chunk + wrh*4096 + mi*1024 + lane*16 (lane-linear).
__global__ __launch_bounds__(256) void quant_all_kernel(const float* __restrict__ x,
                                                        const float* __restrict__ w,
                                                        signed char* __restrict__ qx,
                                                        int* __restrict__ qw,
                                                        const unsigned* __restrict__ mbits) {
    if (blockIdx.x < NBLK_QX) {
        __shared__ signed char tile[WW * 132];
        const int bh = blockIdx.x;
        const int b = bh / HH, h = bh % HH;
        const float s = __uint_as_float(mbits[0]) / QDIV;
        const float* src = x + (size_t)b * (CIN * HH * WW) + (size_t)h * WW;
        #pragma unroll
        for (int i = 0; i < 7; ++i) {                 // 128 ci * 14 float4 = 1792
            int e = threadIdx.x + i * 256;
            int ci = e / 14, wq = e - ci * 14;
            float4 v = *(const float4*)(src + (size_t)ci * (HH * WW) + wq * 4);
            float qa = fminf(fmaxf(rintf(v.x / s), -8.f), 7.f);
            float qb = fminf(fmaxf(rintf(v.y / s), -8.f), 7.f);
            float qc = fminf(fmaxf(rintf(v.z / s), -8.f), 7.f);
            float qd = fminf(fmaxf(rintf(v.w / s), -8.f), 7.f);
            signed char* tp = &tile[(wq * 4) * 132 + ci];
            tp[0]   = (signed char)qa;
            tp[132] = (signed char)qb;
            tp[264] = (signed char)qc;
            tp[396] = (signed char)qd;
        }
        __syncthreads();
        int* dst = (int*)(qx + (size_t)bh * ROWB);
        #pragma unroll
        for (int i = 0; i < 9; ++i) {                 // 2112 dwords
            int d = threadIdx.x + i * 256;
            if (d < ROWB / 4) {
                int u = d >> 2, dw = d & 3;
                int c = u / NSLOT, s2 = u - c * NSLOT;
                int v = 0;
                if (s2 >= 1 && s2 <= WW)
                    v = *(const int*)&tile[(s2 - 1) * 132 + c * 16 + dw * 4];
                dst[d] = v;
            }
        }
    } else {
        int d = (blockIdx.x - NBLK_QX) * 256 + threadIdx.x;  // 73728 dwords
        int k  = d >> 11;                 // chunk 0..35
        int u  = d & 2047;
        int wrh  = u >> 10;
        int mi   = (u >> 8) & 3;
        int jh   = (u >> 7) & 1;
        int co31 = (u >> 2) & 31;
        int jl4  = u & 3;
        int co = wrh * 128 + mi * 32 + co31;
        int t = k >> 2, cc = k & 3;
        int kh = t / 3, kw = t - kh * 3;
        float s = __uint_as_float(mbits[1]) / QDIV;
        int pack = 0;
        #pragma unroll
        for (int j = 0; j < 4; ++j) {
            int ci = cc * 32 + jh * 16 + jl4 * 4 + j;
            float v = w[(((size_t)co * CIN + ci) * 3 + kh) * 3 + kw];
            float q = fminf(fmaxf(rintf(v / s), -8.f), 7.f);
            pack |= (((int)q) & 0xFF) << (8 * j);
        }
        qw[d] = pack;
    }
}

// ---------- conv: i8-MFMA, phase-disciplined (raw barriers + counted vmcnt) ----------
// Block: 256 thr / 4 waves; 256 co x 2 rows. Wave (wr=wid&1: co-half,
// wc=wid>>1: row) computes 128 co x 64 px -> acc[4][2]. LDS: x rows (33.8 KB) +
// 4-deep 8KB weight ring = 65 KB -> 2 blocks/CU. Per k-chunk phase:
// {6 ds_read; stage k+3; vmcnt(4); s_barrier; setprio(1) 8xMFMA setprio(0);
//  s_barrier}. vmcnt never drains to 0 in steady state (T3+T4+T5).
__global__ __launch_bounds__(256, 2) void conv_mfma_kernel(
        const signed char* __restrict__ qxz,   // [zero row | qx rows]
        const signed char* __restrict__ qw3,
        const unsigned* __restrict__ mbits,
        const float* __restrict__ bias,
        float* __restrict__ out) {
    __shared__ signed char lds[LDS_TOTAL];

    // XCD-chunked swizzle (896 % 8 == 0 -> bijective)
    const int sbid = (blockIdx.x & 7) * 112 + (blockIdx.x >> 3);
    const int b  = sbid / 28;
    const int h0 = (sbid % 28) * 2;

    const int tid   = threadIdx.x;
    const int wid   = tid >> 6;
    const int lane  = tid & 63;
    const int l31   = tid & 31;
    const int lhalf = (tid >> 5) & 1;
    const int wr    = wid & 1;    // co half
    const int wc    = wid >> 1;   // row 0/1

    // ---- prologue: stage x rows h0-1..h0+2 (2112 units) + weight chunks 0..2 ----
    #pragma unroll
    for (int i = 0; i < 9; ++i) {
        const int u = tid + i * 256;
        if (u < 2112) {
            const int r = u / 528, c = u - r * 528;
            const int hy = h0 - 1 + r;
            const signed char* src = (hy >= 0 && hy < HH)
                ? qxz + (size_t)(1 + b * HH + hy) * ROWB + c * 16
                : qxz + c * 16;
            load_lds16(src, lds + u * 16);
        }
    }
    #pragma unroll
    for (int kk = 0; kk < 3; ++kk) {
        const signed char* gs = qw3 + kk * WCHUNK + tid * 16;
        signed char* ls = lds + XLDS + kk * WCHUNK + tid * 16;
        load_lds16(gs, ls);
        load_lds16(gs + 4096, ls + 4096);
    }
    asm volatile("s_waitcnt vmcnt(4)" ::: "memory");   // x + chunk0 complete
    __builtin_amdgcn_s_barrier();

    v16i acc[4][2];
    #pragma unroll
    for (int mi = 0; mi < 4; ++mi)
        #pragma unroll
        for (int ni = 0; ni < 2; ++ni)
            #pragma unroll
            for (int r = 0; r < 16; ++r) acc[mi][ni][r] = 0;

    #pragma unroll
    for (int k = 0; k < 36; ++k) {
        const int t = k >> 2, cc = k & 3;
        const int kh = t / 3, kw = t - kh * 3;

        // A fragments (lane-linear, conflict-free)
        const signed char* ap = lds + XLDS + (k & 3) * WCHUNK + (wr << 12) + lane * 16;
        const v4i a0 = *(const v4i*)ap;
        const v4i a1 = *(const v4i*)(ap + 1024);
        const v4i a2 = *(const v4i*)(ap + 2048);
        const v4i a3 = *(const v4i*)(ap + 3072);
        // B fragments (bank-spread: +1056 B between lane halves)
        const signed char* xp = lds + (wc + kh) * ROWB
                                + (cc * 2 + lhalf) * CSTRIDE + (l31 + kw) * 16;
        const v4i b0 = *(const v4i*)xp;
        const v4i b1 = *(const v4i*)(xp + 512);

        // stage chunk k+3 into ring slot (k+3)&3
        if (k + 3 < 36) {
            const signed char* gs = qw3 + (k + 3) * WCHUNK + tid * 16;
            signed char* ls = lds + XLDS + ((k + 3) & 3) * WCHUNK + tid * 16;
            load_lds16(gs, ls);
            load_lds16(gs + 4096, ls + 4096);
        }

        // counted vmcnt: chunk k+1 confirmed done; k+2/k+3 stay in flight
        if (k <= 32)      { asm volatile("s_waitcnt vmcnt(4)" ::: "memory"); }
        else if (k == 33) { asm volatile("s_waitcnt vmcnt(2)" ::: "memory"); }
        else if (k == 34) { asm volatile("s_waitcnt vmcnt(0)" ::: "memory"); }
        __builtin_amdgcn_s_barrier();

        __builtin_amdgcn_s_setprio(1);
        acc[0][0] = __builtin_amdgcn_mfma_i32_32x32x32_i8(a0, b0, acc[0][0], 0, 0, 0);
        acc[1][0] = __builtin_amdgcn_mfma_i32_32x32x32_i8(a1, b0, acc[1][0], 0, 0, 0);
        acc[2][0] = __builtin_amdgcn_mfma_i32_32x32x32_i8(a2, b0, acc[2][0], 0, 0, 0);
        acc[3][0] = __builtin_amdgcn_mfma_i32_32x32x32_i8(a3, b0, acc[3][0], 0, 0, 0);
        acc[0][1] = __builtin_amdgcn_mfma_i32_32x32x32_i8(a0, b1, acc[0][1], 0, 0, 0);
        acc[1][1] = __builtin_amdgcn_mfma_i32_32x32x32_i8(a1, b1, acc[1][1], 0, 0, 0);
        acc[2][1] = __builtin_amdgcn_mfma_i32_32x32x32_i8(a2, b1, acc[2][1], 0, 0, 0);
        acc[3][1] = __builtin_amdgcn_mfma_i32_32x32x32_i8(a3, b1, acc[3][1], 0, 0, 0);
        __builtin_amdgcn_s_setprio(0);

        if (k < 35) __builtin_amdgcn_s_barrier();
    }

    // ---- epilogue: dequant + bias ----
    const float s = (__uint_as_float(mbits[0]) / QDIV) *
                    (__uint_as_float(mbits[1]) / QDIV);
    const int hrow = h0 + wc;
    #pragma unroll
    for (int mi = 0; mi < 4; ++mi) {
        #pragma unroll
        for (int r = 0; r < 16; ++r) {
            const int co = wr * 128 + mi * 32 + (r & 3) + 8 * (r >> 2) + 4 * lhalf;
            const float bv = bias[co];
            float* orow = out + ((size_t)(b * COUT + co) * HH + hrow) * WW;
            orow[l31] = (float)acc[mi][0][r] * s + bv;
            if (l31 < WW - 32) orow[32 + l31] = (float)acc[mi][1][r] * s + bv;
        }
    }
}

extern "C" void kernel_launch(void* const* d_in, const int* in_sizes, int n_in,
                              void* d_out, int out_size, void* d_ws, size_t ws_size,
                              hipStream_t stream) {
    const float* x    = (const float*)d_in[0];
    const float* w    = (const float*)d_in[1];
    const float* bias = (const float*)d_in[2];
    float* out = (float*)d_out;

    unsigned* mbits = (unsigned*)d_ws;
    signed char* qxz = (signed char*)d_ws + 256;     // [zero row | qx rows]
    signed char* qx  = qxz + ROWB;
    signed char* qw3 = qx + (size_t)B_ * HH * ROWB;

    hipMemsetAsync(d_ws, 0, 256 + ROWB, stream);     // mbits + zero row
    hipLaunchKernelGGL(absmax_all_kernel, dim3(NBLK_AX + NBLK_AW), dim3(256), 0, stream,
                       x, w, mbits);
    hipLaunchKernelGGL(quant_all_kernel, dim3(NBLK_QX + NBLK_QW), dim3(256), 0, stream,
                       x, w, qx, (int*)qw3, mbits);
    hipLaunchKernelGGL(conv_mfma_kernel, dim3(B_ * 28), dim3(256), 0, stream,
                       qxz, qw3, mbits, bias, out);
}

// Round 13
// 106.404 us; speedup vs baseline: 1.1338x; 1.0019x over previous
//
#include <hip/hip_runtime.h>
#include <stdint.h>

#define B_   32
#define CIN  128
#define HH   56
#define WW   56
#define COUT 256
#define QDIV 7.5f

#define NBLK_AX 2048
#define NBLK_AW 288
#define NBLK_QX (B_ * HH)   // 1792
#define NBLK_QW 288

#define NSLOT 58
#define CSTRIDE (NSLOT * 16)       // 928 B per ci-chunk
#define ROWB (8 * CSTRIDE)         // 7424 B per image row
#define XLDS (4 * ROWB)            // 29696 (rows h0-1..h0+2)
#define WCHUNK 8192                // one k-chunk: 256 co x 32 ci
#define NRING 6
#define LDS_TOTAL (XLDS + NRING * WCHUNK)  // 78848 -> 2 blocks/CU

typedef int v4i  __attribute__((ext_vector_type(4)));
typedef int v16i __attribute__((ext_vector_type(16)));

typedef __attribute__((address_space(3))) unsigned char lds_u8;
typedef __attribute__((address_space(1))) const unsigned char glb_u8;

__device__ __forceinline__ void load_lds16(const void* g, void* l) {
    __builtin_amdgcn_global_load_lds((glb_u8*)g, (lds_u8*)l, 16, 0, 0);
}

// ---------- absmax: blocks [0,2048) -> x, [2048,2336) -> w ----------
__global__ __launch_bounds__(256) void absmax_all_kernel(const float* __restrict__ x,
                                                         const float* __restrict__ w,
                                                         unsigned* __restrict__ mbits) {
    const float* p; int n4, i, stride; unsigned* slot;
    if (blockIdx.x < NBLK_AX) {
        p = x; n4 = B_ * CIN * HH * WW / 4;
        i = blockIdx.x * 256 + threadIdx.x; stride = NBLK_AX * 256; slot = mbits;
    } else {
        p = w; n4 = COUT * CIN * 9 / 4;
        i = (blockIdx.x - NBLK_AX) * 256 + threadIdx.x; stride = NBLK_AW * 256; slot = mbits + 1;
    }
    float m = 0.f;
    for (; i < n4; i += stride) {
        float4 v = ((const float4*)p)[i];
        m = fmaxf(m, fmaxf(fmaxf(fabsf(v.x), fabsf(v.y)),
                           fmaxf(fabsf(v.z), fabsf(v.w))));
    }
    #pragma unroll
    for (int off = 32; off; off >>= 1) m = fmaxf(m, __shfl_down(m, off));
    __shared__ float red[4];
    int lane = threadIdx.x & 63, wv = threadIdx.x >> 6;
    if (lane == 0) red[wv] = m;
    __syncthreads();
    if (threadIdx.x == 0) {
        m = fmaxf(fmaxf(red[0], red[1]), fmaxf(red[2], red[3]));
        atomicMax(slot, __float_as_uint(m));
    }
}

// ---------- quantize: blocks [0,1792) -> x, [1792,2080) -> w ----------
// qx: per (b,h) row of 7424 B: byte = c*928 + s*16 + j; slot s in [1,56] holds
//     pixel w = s-1, ci = c*16+j; slots 0 and 57 zero.
// qw3 (chunk-major): byte = k*8192 + wrh*4096 + mi*1024 + jh*512 + co31*16 + jl
//   co = wrh*128 + mi*32 + co31, k = (kh*3+kw)*4 + cc, ci = cc*32 + jh*16 + jl.
__global__ __launch_bounds__(256) void quant_all_kernel(const float* __restrict__ x,
                                                        const float* __restrict__ w,
                                                        signed char* __restrict__ qx,
                                                        int* __restrict__ qw,
                                                        const unsigned* __restrict__ mbits) {
    if (blockIdx.x < NBLK_QX) {
        __shared__ signed char tile[WW * 132];
        const int bh = blockIdx.x;
        const int b = bh / HH, h = bh % HH;
        const float s = __uint_as_float(mbits[0]) / QDIV;
        const float* src = x + (size_t)b * (CIN * HH * WW) + (size_t)h * WW;
        #pragma unroll
        for (int i = 0; i < 7; ++i) {                 // 128 ci * 14 float4 = 1792
            int e = threadIdx.x + i * 256;
            int ci = e / 14, wq = e - ci * 14;
            float4 v = *(const float4*)(src + (size_t)ci * (HH * WW) + wq * 4);
            float qa = fminf(fmaxf(rintf(v.x / s), -8.f), 7.f);
            float qb = fminf(fmaxf(rintf(v.y / s), -8.f), 7.f);
            float qc = fminf(fmaxf(rintf(v.z / s), -8.f), 7.f);
            float qd = fminf(fmaxf(rintf(v.w / s), -8.f), 7.f);
            signed char* tp = &tile[(wq * 4) * 132 + ci];
            tp[0]   = (signed char)qa;
            tp[132] = (signed char)qb;
            tp[264] = (signed char)qc;
            tp[396] = (signed char)qd;
        }
        __syncthreads();
        int* dst = (int*)(qx + (size_t)bh * ROWB);
        #pragma unroll
        for (int i = 0; i < 8; ++i) {                 // 1856 dwords
            int d = threadIdx.x + i * 256;
            if (d < ROWB / 4) {
                int u = d >> 2, dw = d & 3;
                int c = u / NSLOT, s2 = u - c * NSLOT;
                int v = 0;
                if (s2 >= 1 && s2 <= WW)
                    v = *(const int*)&tile[(s2 - 1) * 132 + c * 16 + dw * 4];
                dst[d] = v;
            }
        }
    } else {
        int d = (blockIdx.x - NBLK_QX) * 256 + threadIdx.x;  // 73728 dwords
        int k  = d >> 11;                 // chunk 0..35
        int u  = d & 2047;
        int wrh  = u >> 10;
        int mi   = (u >> 8) & 3;
        int jh   = (u >> 7) & 1;
        int co31 = (u >> 2) & 31;
        int jl4  = u & 3;
        int co = wrh * 128 + mi * 32 + co31;
        int t = k >> 2, cc = k & 3;
        int kh = t / 3, kw = t - kh * 3;
        float s = __uint_as_float(mbits[1]) / QDIV;
        int pack = 0;
        #pragma unroll
        for (int j = 0; j < 4; ++j) {
            int ci = cc * 32 + jh * 16 + jl4 * 4 + j;
            float v = w[(((size_t)co * CIN + ci) * 3 + kh) * 3 + kw];
            float q = fminf(fmaxf(rintf(v / s), -8.f), 7.f);
            pack |= (((int)q) & 0xFF) << (8 * j);
        }
        qw[d] = pack;
    }
}

// ---------- conv: i8-MFMA, register-double-buffered frags, 6-deep LDS ring ----------
// Block: 256 thr / 4 waves; 256 co x 2 rows; wave (wr,wc) = 128co x 64px,
// acc[4][2]. Iter k: {stage(k+3)->slot (k+3)%6; vmcnt(4); s_barrier;
// prefetch frags(k+1)->NXT regs (no wait); 8 MFMA on CUR regs}. Race-freedom:
// chunk k+1 confirmed by every wave's vmcnt(4) BEFORE barrier(k); ring-6 puts
// one full barrier between last read of a slot and its overwrite issue.
__global__ __launch_bounds__(256, 2) void conv_mfma_kernel(
        const signed char* __restrict__ qxz,   // [zero row | qx rows]
        const signed char* __restrict__ qw3,
        const unsigned* __restrict__ mbits,
        const float* __restrict__ bias,
        float* __restrict__ out) {
    __shared__ signed char lds[LDS_TOTAL];

    // XCD-chunked swizzle (896 % 8 == 0 -> bijective)
    const int sbid = (blockIdx.x & 7) * 112 + (blockIdx.x >> 3);
    const int b  = sbid / 28;
    const int h0 = (sbid % 28) * 2;

    const int tid   = threadIdx.x;
    const int wid   = tid >> 6;
    const int lane  = tid & 63;
    const int l31   = tid & 31;
    const int lhalf = (tid >> 5) & 1;
    const int wr    = wid & 1;    // co half
    const int wc    = wid >> 1;   // row 0/1

    // ---- prologue: stage x rows h0-1..h0+2 (1856 units) + weight chunks 0..2 ----
    #pragma unroll
    for (int i = 0; i < 8; ++i) {
        const int u = tid + i * 256;
        if (u < 1856) {
            const int r = u / 464, c = u - r * 464;
            const int hy = h0 - 1 + r;
            const signed char* src = (hy >= 0 && hy < HH)
                ? qxz + (size_t)(1 + b * HH + hy) * ROWB + c * 16
                : qxz + c * 16;
            load_lds16(src, lds + u * 16);
        }
    }
    #pragma unroll
    for (int kk = 0; kk < 3; ++kk) {
        const signed char* gs = qw3 + kk * WCHUNK + tid * 16;
        signed char* ls = lds + XLDS + kk * WCHUNK + tid * 16;
        load_lds16(gs, ls);
        load_lds16(gs + 4096, ls + 4096);
    }
    asm volatile("s_waitcnt vmcnt(4)" ::: "memory");   // x + chunk0 landed
    __builtin_amdgcn_s_barrier();
    __builtin_amdgcn_sched_barrier(0);

    v16i acc[4][2];
    #pragma unroll
    for (int mi = 0; mi < 4; ++mi)
        #pragma unroll
        for (int ni = 0; ni < 2; ++ni)
            #pragma unroll
            for (int r = 0; r < 16; ++r) acc[mi][ni][r] = 0;

    v4i Aa[4], Ab[4], Ba[2], Bb[2];
    // prefetch chunk 0 fragments
    {
        const signed char* ap = lds + XLDS + (wr << 12) + lane * 16;
        Aa[0] = *(const v4i*)ap;
        Aa[1] = *(const v4i*)(ap + 1024);
        Aa[2] = *(const v4i*)(ap + 2048);
        Aa[3] = *(const v4i*)(ap + 3072);
        const signed char* xp = lds + wc * ROWB + lhalf * CSTRIDE + l31 * 16;  // k=0
        Ba[0] = *(const v4i*)xp;
        Ba[1] = *(const v4i*)(xp + 512);
    }

#define STEP(K, CA, CB, NA, NB)                                                              \
    {                                                                                        \
        if ((K) + 3 < 36) {                                                                  \
            const signed char* gs_ = qw3 + ((K) + 3) * WCHUNK + tid * 16;                    \
            signed char* ls_ = lds + XLDS + (((K) + 3) % NRING) * WCHUNK + tid * 16;         \
            load_lds16(gs_, ls_);                                                            \
            load_lds16(gs_ + 4096, ls_ + 4096);                                              \
        }                                                                                    \
        if ((K) <= 32)      { asm volatile("s_waitcnt vmcnt(4)" ::: "memory"); }             \
        else if ((K) == 33) { asm volatile("s_waitcnt vmcnt(0)" ::: "memory"); }             \
        if ((K) < 35) {                                                                      \
            __builtin_amdgcn_s_barrier();                                                    \
            __builtin_amdgcn_sched_barrier(0);                                               \
        }                                                                                    \
        if ((K) + 1 < 36) {                                                                  \
            const int kn_ = (K) + 1;                                                         \
            const int tn_ = kn_ >> 2, ccn_ = kn_ & 3;                                        \
            const int khn_ = tn_ / 3, kwn_ = tn_ - khn_ * 3;                                 \
            const signed char* apn_ = lds + XLDS + (kn_ % NRING) * WCHUNK                    \
                                      + (wr << 12) + lane * 16;                              \
            NA[0] = *(const v4i*)apn_;                                                       \
            NA[1] = *(const v4i*)(apn_ + 1024);                                              \
            NA[2] = *(const v4i*)(apn_ + 2048);                                              \
            NA[3] = *(const v4i*)(apn_ + 3072);                                              \
            const signed char* xpn_ = lds + (wc + khn_) * ROWB                               \
                                      + (ccn_ * 2 + lhalf) * CSTRIDE + (l31 + kwn_) * 16;    \
            NB[0] = *(const v4i*)xpn_;                                                       \
            NB[1] = *(const v4i*)(xpn_ + 512);                                               \
        }                                                                                    \
        acc[0][0] = __builtin_amdgcn_mfma_i32_32x32x32_i8(CA[0], CB[0], acc[0][0], 0, 0, 0); \
        acc[1][0] = __builtin_amdgcn_mfma_i32_32x32x32_i8(CA[1], CB[0], acc[1][0], 0, 0, 0); \
        acc[2][0] = __builtin_amdgcn_mfma_i32_32x32x32_i8(CA[2], CB[0], acc[2][0], 0, 0, 0); \
        acc[3][0] = __builtin_amdgcn_mfma_i32_32x32x32_i8(CA[3], CB[0], acc[3][0], 0, 0, 0); \
        acc[0][1] = __builtin_amdgcn_mfma_i32_32x32x32_i8(CA[0], CB[1], acc[0][1], 0, 0, 0); \
        acc[1][1] = __builtin_amdgcn_mfma_i32_32x32x32_i8(CA[1], CB[1], acc[1][1], 0, 0, 0); \
        acc[2][1] = __builtin_amdgcn_mfma_i32_32x32x32_i8(CA[2], CB[1], acc[2][1], 0, 0, 0); \
        acc[3][1] = __builtin_amdgcn_mfma_i32_32x32x32_i8(CA[3], CB[1], acc[3][1], 0, 0, 0); \
    }

    #pragma unroll
    for (int kk = 0; kk < 18; ++kk) {
        STEP(kk * 2,     Aa, Ba, Ab, Bb)
        STEP(kk * 2 + 1, Ab, Bb, Aa, Ba)
    }
#undef STEP

    // ---- epilogue: dequant + bias ----
    const float s = (__uint_as_float(mbits[0]) / QDIV) *
                    (__uint_as_float(mbits[1]) / QDIV);
    const int hrow = h0 + wc;
    #pragma unroll
    for (int mi = 0; mi < 4; ++mi) {
        #pragma unroll
        for (int r = 0; r < 16; ++r) {
            const int co = wr * 128 + mi * 32 + (r & 3) + 8 * (r >> 2) + 4 * lhalf;
            const float bv = bias[co];
            float* orow = out + ((size_t)(b * COUT + co) * HH + hrow) * WW;
            orow[l31] = (float)acc[mi][0][r] * s + bv;
            if (l31 < WW - 32) orow[32 + l31] = (float)acc[mi][1][r] * s + bv;
        }
    }
}

extern "C" void kernel_launch(void* const* d_in, const int* in_sizes, int n_in,
                              void* d_out, int out_size, void* d_ws, size_t ws_size,
                              hipStream_t stream) {
    const float* x    = (const float*)d_in[0];
    const float* w    = (const float*)d_in[1];
    const float* bias = (const float*)d_in[2];
    float* out = (float*)d_out;

    unsigned* mbits = (unsigned*)d_ws;
    signed char* qxz = (signed char*)d_ws + 256;     // [zero row | qx rows]
    signed char* qx  = qxz + ROWB;
    signed char* qw3 = qx + (size_t)B_ * HH * ROWB;

    hipMemsetAsync(d_ws, 0, 256 + ROWB, stream);     // mbits + zero row
    hipLaunchKernelGGL(absmax_all_kernel, dim3(NBLK_AX + NBLK_AW), dim3(256), 0, stream,
                       x, w, mbits);
    hipLaunchKernelGGL(quant_all_kernel, dim3(NBLK_QX + NBLK_QW), dim3(256), 0, stream,
                       x, w, qx, (int*)qw3, mbits);
    hipLaunchKernelGGL(conv_mfma_kernel, dim3(B_ * 28), dim3(256), 0, stream,
                       qxz, qw3, mbits, bias, out);
}

// Round 14
// 103.729 us; speedup vs baseline: 1.1630x; 1.0258x over previous
//
#include <hip/hip_runtime.h>
#include <stdint.h>

#define B_   32
#define CIN  128
#define HH   56
#define WW   56
#define COUT 256
#define QDIV 7.5f

#define NBLK_AX 2048
#define NBLK_AW 288
#define NBLK_QX (B_ * HH)   // 1792
#define NBLK_QW 288

#define NSLOT 58
#define CSTRIDE (NSLOT * 16)       // 928 B per ci-chunk
#define ROWB (8 * CSTRIDE)         // 7424 B per image row
#define XLDS (6 * ROWB)            // 44544 (rows h0-1..h0+4)
#define WSEG 2048                  // one k-chunk for a 64-co group
#define NRING 3
#define LDS_TOTAL (XLDS + NRING * WSEG)   // 50688 -> 3 blocks/CU
#define WGRP 73728                 // 72 KB weights per 64-co group

typedef int v4i  __attribute__((ext_vector_type(4)));
typedef int v16i __attribute__((ext_vector_type(16)));

typedef __attribute__((address_space(3))) unsigned char lds_u8;
typedef __attribute__((address_space(1))) const unsigned char glb_u8;

__device__ __forceinline__ void load_lds16(const void* g, void* l) {
    __builtin_amdgcn_global_load_lds((glb_u8*)g, (lds_u8*)l, 16, 0, 0);
}

// ---------- absmax: blocks [0,2048) -> x, [2048,2336) -> w ----------
__global__ __launch_bounds__(256) void absmax_all_kernel(const float* __restrict__ x,
                                                         const float* __restrict__ w,
                                                         unsigned* __restrict__ mbits) {
    const float* p; int n4, i, stride; unsigned* slot;
    if (blockIdx.x < NBLK_AX) {
        p = x; n4 = B_ * CIN * HH * WW / 4;
        i = blockIdx.x * 256 + threadIdx.x; stride = NBLK_AX * 256; slot = mbits;
    } else {
        p = w; n4 = COUT * CIN * 9 / 4;
        i = (blockIdx.x - NBLK_AX) * 256 + threadIdx.x; stride = NBLK_AW * 256; slot = mbits + 1;
    }
    float m = 0.f;
    for (; i < n4; i += stride) {
        float4 v = ((const float4*)p)[i];
        m = fmaxf(m, fmaxf(fmaxf(fabsf(v.x), fabsf(v.y)),
                           fmaxf(fabsf(v.z), fabsf(v.w))));
    }
    #pragma unroll
    for (int off = 32; off; off >>= 1) m = fmaxf(m, __shfl_down(m, off));
    __shared__ float red[4];
    int lane = threadIdx.x & 63, wv = threadIdx.x >> 6;
    if (lane == 0) red[wv] = m;
    __syncthreads();
    if (threadIdx.x == 0) {
        m = fmaxf(fmaxf(red[0], red[1]), fmaxf(red[2], red[3]));
        atomicMax(slot, __float_as_uint(m));
    }
}

// ---------- quantize: x blocks, w blocks, + 1 zero-row block ----------
// qx: per (b,h) row of 7424 B: byte = c*928 + s*16 + j; slot s in [1,56] holds
//     pixel w = s-1, ci = c*16+j; slots 0 and 57 zero.
// qw3: byte = g*73728 + k*2048 + mi*1024 + jh*512 + co31*16 + jl
//   co = g*64 + mi*32 + co31, k = (kh*3+kw)*4 + cc, ci = cc*32 + jh*16 + jl.
__global__ __launch_bounds__(256) void quant_all_kernel(const float* __restrict__ x,
                                                        const float* __restrict__ w,
                                                        signed char* __restrict__ qx,
                                                        int* __restrict__ qw,
                                                        signed char* __restrict__ qxzero,
                                                        const unsigned* __restrict__ mbits) {
    if (blockIdx.x < NBLK_QX) {
        __shared__ signed char tile[WW * 132];
        const int bh = blockIdx.x;
        const int b = bh / HH, h = bh % HH;
        const float s = __uint_as_float(mbits[0]) / QDIV;
        const float* src = x + (size_t)b * (CIN * HH * WW) + (size_t)h * WW;
        #pragma unroll
        for (int i = 0; i < 7; ++i) {                 // 128 ci * 14 float4 = 1792
            int e = threadIdx.x + i * 256;
            int ci = e / 14, wq = e - ci * 14;
            float4 v = *(const float4*)(src + (size_t)ci * (HH * WW) + wq * 4);
            float qa = fminf(fmaxf(rintf(v.x / s), -8.f), 7.f);
            float qb = fminf(fmaxf(rintf(v.y / s), -8.f), 7.f);
            float qc = fminf(fmaxf(rintf(v.z / s), -8.f), 7.f);
            float qd = fminf(fmaxf(rintf(v.w / s), -8.f), 7.f);
            signed char* tp = &tile[(wq * 4) * 132 + ci];
            tp[0]   = (signed char)qa;
            tp[132] = (signed char)qb;
            tp[264] = (signed char)qc;
            tp[396] = (signed char)qd;
        }
        __syncthreads();
        int* dst = (int*)(qx + (size_t)bh * ROWB);
        #pragma unroll
        for (int i = 0; i < 8; ++i) {                 // 1856 dwords
            int d = threadIdx.x + i * 256;
            if (d < ROWB / 4) {
                int u = d >> 2, dw = d & 3;
                int c = u / NSLOT, s2 = u - c * NSLOT;
                int v = 0;
                if (s2 >= 1 && s2 <= WW)
                    v = *(const int*)&tile[(s2 - 1) * 132 + c * 16 + dw * 4];
                dst[d] = v;
            }
        }
    } else if (blockIdx.x < NBLK_QX + NBLK_QW) {
        int d = (blockIdx.x - NBLK_QX) * 256 + threadIdx.x;  // 73728 dwords
        int g  = d / 18432;
        int r1 = d - g * 18432;
        int k  = r1 >> 9;
        int q9 = r1 & 511;
        int mi = q9 >> 8;
        int u2 = q9 & 255;
        int jh = u2 >> 7;
        int co31 = (u2 >> 2) & 31;
        int jl4  = u2 & 3;
        int co = g * 64 + mi * 32 + co31;
        int t = k >> 2, cc = k & 3;
        int kh = t / 3, kw = t - kh * 3;
        float s = __uint_as_float(mbits[1]) / QDIV;
        int pack = 0;
        #pragma unroll
        for (int j = 0; j < 4; ++j) {
            int ci = cc * 32 + jh * 16 + jl4 * 4 + j;
            float v = w[(((size_t)co * CIN + ci) * 3 + kh) * 3 + kw];
            float q = fminf(fmaxf(rintf(v / s), -8.f), 7.f);
            pack |= (((int)q) & 0xFF) << (8 * j);
        }
        qw[d] = pack;
    } else {
        // zero-row block: clear the shared border row (464 x 16B)
        for (int d = threadIdx.x; d < ROWB / 16; d += 256)
            ((int4*)qxzero)[d] = int4{0, 0, 0, 0};
    }
}

// ---------- conv: i8-MFMA, 3 blocks/CU, ring-3 counted-vmcnt (never drains) ----------
// Block: 256 thr / 4 waves; 64 co (group g) x 4 output rows; wave = 64co x 56px,
// acc[2][2]. LDS: x rows h0-1..h0+4 (44.5 KB) + ring 3 x 2KB = 50.7 KB -> 3
// blocks/CU (12 waves, 3/SIMD). Iter k: {stage(k+2) by waves 0-1;
// ds_read seg k + 4 MFMA; vmcnt(1); s_barrier}. Race-free: seg k confirmed by
// stagers' vmcnt(1)@k-1 + barrier(k-1); slot overwrite one barrier after last read.
__global__ __launch_bounds__(256, 3) void conv_mfma_kernel(
        const signed char* __restrict__ qxz,   // [zero row | qx rows]
        const signed char* __restrict__ qw3,
        const unsigned* __restrict__ mbits,
        const float* __restrict__ bias,
        float* __restrict__ out) {
    __shared__ signed char lds[LDS_TOTAL];

    // XCD-chunked swizzle (1792 % 8 == 0 -> bijective); g fastest in a chunk
    const int sbid = (blockIdx.x & 7) * 224 + (blockIdx.x >> 3);
    const int g    = sbid & 3;
    const int brg  = sbid >> 2;       // 0..447
    const int rg   = brg % 14;
    const int b    = brg / 14;
    const int h0   = rg * 4;

    const int tid    = threadIdx.x;
    const int rowidx = tid >> 6;      // wave id = output row 0..3
    const int lane   = tid & 63;
    const int l31    = tid & 31;
    const int lhalf  = (tid >> 5) & 1;

    const signed char* wgrp = qw3 + (size_t)g * WGRP;

    // ---- prologue: x rows h0-1..h0+4 (2784 units) + weight segs 0,1 ----
    #pragma unroll
    for (int i = 0; i < 11; ++i) {
        const int u = tid + i * 256;
        if (u < 2784) {
            const int r = u / 464, c = u - r * 464;
            const int hy = h0 - 1 + r;
            const signed char* src = (hy >= 0 && hy < HH)
                ? qxz + (size_t)(1 + b * HH + hy) * ROWB + c * 16
                : qxz + c * 16;
            load_lds16(src, lds + u * 16);
        }
    }
    if (tid < 128) {
        load_lds16(wgrp + tid * 16,        lds + XLDS + tid * 16);
        load_lds16(wgrp + 2048 + tid * 16, lds + XLDS + 2048 + tid * 16);
    }
    __syncthreads();   // one full drain (prologue only)

    v16i acc[2][2];
    #pragma unroll
    for (int mi = 0; mi < 2; ++mi)
        #pragma unroll
        for (int ni = 0; ni < 2; ++ni)
            #pragma unroll
            for (int r = 0; r < 16; ++r) acc[mi][ni][r] = 0;

    #pragma unroll
    for (int k = 0; k < 36; ++k) {
        // stage seg k+2 into ring slot (k+2)%3 (waves 0-1 only; 2KB)
        if (k + 2 < 36) {
            if (tid < 128)
                load_lds16(wgrp + (k + 2) * WSEG + tid * 16,
                           lds + XLDS + ((k + 2) % NRING) * WSEG + tid * 16);
        }

        // compute seg k (published by barrier(k-1))
        const int t = k >> 2, cc = k & 3;
        const int kh = t / 3, kw = t - kh * 3;
        const signed char* ap = lds + XLDS + (k % NRING) * WSEG + lane * 16;
        const v4i a0 = *(const v4i*)ap;
        const v4i a1 = *(const v4i*)(ap + 1024);
        const signed char* xp = lds + (rowidx + kh) * ROWB
                                + (cc * 2 + lhalf) * CSTRIDE + (l31 + kw) * 16;
        const v4i b0 = *(const v4i*)xp;
        const v4i b1 = *(const v4i*)(xp + 512);
        acc[0][0] = __builtin_amdgcn_mfma_i32_32x32x32_i8(a0, b0, acc[0][0], 0, 0, 0);
        acc[1][0] = __builtin_amdgcn_mfma_i32_32x32x32_i8(a1, b0, acc[1][0], 0, 0, 0);
        acc[0][1] = __builtin_amdgcn_mfma_i32_32x32x32_i8(a0, b1, acc[0][1], 0, 0, 0);
        acc[1][1] = __builtin_amdgcn_mfma_i32_32x32x32_i8(a1, b1, acc[1][1], 0, 0, 0);

        // counted vmcnt: confirm seg k+1 for next iter; keep seg k+2 in flight
        if (k < 34)       { asm volatile("s_waitcnt vmcnt(1)" ::: "memory"); }
        else if (k == 34) { asm volatile("s_waitcnt vmcnt(0)" ::: "memory"); }
        if (k < 35) {
            __builtin_amdgcn_s_barrier();
            __builtin_amdgcn_sched_barrier(0);
        }
    }

    // ---- epilogue: dequant + bias ----
    const float s = (__uint_as_float(mbits[0]) / QDIV) *
                    (__uint_as_float(mbits[1]) / QDIV);
    const int hrow = h0 + rowidx;
    #pragma unroll
    for (int mi = 0; mi < 2; ++mi) {
        #pragma unroll
        for (int r = 0; r < 16; ++r) {
            const int co = g * 64 + mi * 32 + (r & 3) + 8 * (r >> 2) + 4 * lhalf;
            const float bv = bias[co];
            float* orow = out + ((size_t)(b * COUT + co) * HH + hrow) * WW;
            orow[l31] = (float)acc[mi][0][r] * s + bv;
            if (l31 < WW - 32) orow[32 + l31] = (float)acc[mi][1][r] * s + bv;
        }
    }
}

extern "C" void kernel_launch(void* const* d_in, const int* in_sizes, int n_in,
                              void* d_out, int out_size, void* d_ws, size_t ws_size,
                              hipStream_t stream) {
    const float* x    = (const float*)d_in[0];
    const float* w    = (const float*)d_in[1];
    const float* bias = (const float*)d_in[2];
    float* out = (float*)d_out;

    unsigned* mbits = (unsigned*)d_ws;
    signed char* qxz = (signed char*)d_ws + 256;     // [zero row | qx rows]
    signed char* qx  = qxz + ROWB;
    signed char* qw3 = qx + (size_t)B_ * HH * ROWB;

    hipMemsetAsync(d_ws, 0, 8, stream);              // mbits only
    hipLaunchKernelGGL(absmax_all_kernel, dim3(NBLK_AX + NBLK_AW), dim3(256), 0, stream,
                       x, w, mbits);
    hipLaunchKernelGGL(quant_all_kernel, dim3(NBLK_QX + NBLK_QW + 1), dim3(256), 0, stream,
                       x, w, qx, (int*)qw3, qxz, mbits);
    hipLaunchKernelGGL(conv_mfma_kernel, dim3(B_ * 14 * 4), dim3(256), 0, stream,
                       qxz, qw3, mbits, bias, out);
}

// Round 15
// 102.187 us; speedup vs baseline: 1.1805x; 1.0151x over previous
//
#include <hip/hip_runtime.h>
#include <stdint.h>

#define B_   32
#define CIN  128
#define HH   56
#define WW   56
#define COUT 256
#define QDIV 7.5f

#define NBLK_AX 2048
#define NBLK_AW 288
#define NBLK_QX (B_ * HH)   // 1792
#define NBLK_QW 288

#define NSLOT 58
#define CSTRIDE (NSLOT * 16)       // 928 B per ci-chunk
#define ROWB (8 * CSTRIDE)         // 7424 B per image row
#define XLDS (6 * ROWB)            // 44544 (rows h0-1..h0+4)
#define WSEG 4096                  // 2 k-chunks for a 64-co group
#define LDS_TOTAL (XLDS + 2 * WSEG)   // 52736 -> 3 blocks/CU
#define WGRP 73728                 // 72 KB weights per 64-co group

typedef int v4i  __attribute__((ext_vector_type(4)));
typedef int v16i __attribute__((ext_vector_type(16)));

typedef __attribute__((address_space(3))) unsigned char lds_u8;
typedef __attribute__((address_space(1))) const unsigned char glb_u8;

__device__ __forceinline__ void load_lds16(const void* g, void* l) {
    __builtin_amdgcn_global_load_lds((glb_u8*)g, (lds_u8*)l, 16, 0, 0);
}

__device__ __forceinline__ int q8(float v, float s) {
    return ((int)fminf(fmaxf(rintf(v / s), -8.f), 7.f)) & 0xFF;
}

// ---------- absmax: blocks [0,2048) -> x, [2048,2336) -> w ----------
__global__ __launch_bounds__(256) void absmax_all_kernel(const float* __restrict__ x,
                                                         const float* __restrict__ w,
                                                         unsigned* __restrict__ mbits) {
    const float* p; int n4, i, stride; unsigned* slot;
    if (blockIdx.x < NBLK_AX) {
        p = x; n4 = B_ * CIN * HH * WW / 4;
        i = blockIdx.x * 256 + threadIdx.x; stride = NBLK_AX * 256; slot = mbits;
    } else {
        p = w; n4 = COUT * CIN * 9 / 4;
        i = (blockIdx.x - NBLK_AX) * 256 + threadIdx.x; stride = NBLK_AW * 256; slot = mbits + 1;
    }
    float m = 0.f;
    for (; i < n4; i += stride) {
        float4 v = ((const float4*)p)[i];
        m = fmaxf(m, fmaxf(fmaxf(fabsf(v.x), fabsf(v.y)),
                           fmaxf(fabsf(v.z), fabsf(v.w))));
    }
    #pragma unroll
    for (int off = 32; off; off >>= 1) m = fmaxf(m, __shfl_down(m, off));
    __shared__ float red[4];
    int lane = threadIdx.x & 63, wv = threadIdx.x >> 6;
    if (lane == 0) red[wv] = m;
    __syncthreads();
    if (threadIdx.x == 0) {
        m = fmaxf(fmaxf(red[0], red[1]), fmaxf(red[2], red[3]));
        atomicMax(slot, __float_as_uint(m));
    }
}

// ---------- quantize: x blocks, w blocks, + 1 zero-row block ----------
// qx: per (b,h) row of 7424 B: byte = c*928 + s*16 + j; slot s in [1,56] holds
//     pixel w = s-1, ci = c*16+j; slots 0 and 57 zero.
// qw3: byte = g*73728 + k*2048 + mi*1024 + jh*512 + co31*16 + jl
//   co = g*64 + mi*32 + co31, k = (kh*3+kw)*4 + cc, ci = cc*32 + jh*16 + jl.
__global__ __launch_bounds__(256) void quant_all_kernel(const float* __restrict__ x,
                                                        const float* __restrict__ w,
                                                        signed char* __restrict__ qx,
                                                        int* __restrict__ qw,
                                                        signed char* __restrict__ qxzero,
                                                        const unsigned* __restrict__ mbits) {
    if (blockIdx.x < NBLK_QX) {
        __shared__ int tile32[WW * 33];               // [w][33 ci-quad dwords]
        const int bh = blockIdx.x;
        const int b = bh / HH, h = bh % HH;
        const float s = __uint_as_float(mbits[0]) / QDIV;
        const float* src = x + (size_t)b * (CIN * HH * WW) + (size_t)h * WW;

        // 32 ci-quads x 14 w-quads = 448 items; dword-granular LDS writes
        for (int it = threadIdx.x; it < 448; it += 256) {
            const int cq = it / 14, wq = it - cq * 14;
            const float* r0 = src + (size_t)(cq * 4 + 0) * (HH * WW);
            const float* r1 = src + (size_t)(cq * 4 + 1) * (HH * WW);
            const float* r2 = src + (size_t)(cq * 4 + 2) * (HH * WW);
            const float* r3 = src + (size_t)(cq * 4 + 3) * (HH * WW);
            const float4 v0 = ((const float4*)r0)[wq];
            const float4 v1 = ((const float4*)r1)[wq];
            const float4 v2 = ((const float4*)r2)[wq];
            const float4 v3 = ((const float4*)r3)[wq];
            int* tp = &tile32[(wq * 4) * 33 + cq];
            tp[0]      = q8(v0.x, s) | (q8(v1.x, s) << 8) | (q8(v2.x, s) << 16) | (q8(v3.x, s) << 24);
            tp[33]     = q8(v0.y, s) | (q8(v1.y, s) << 8) | (q8(v2.y, s) << 16) | (q8(v3.y, s) << 24);
            tp[66]     = q8(v0.z, s) | (q8(v1.z, s) << 8) | (q8(v2.z, s) << 16) | (q8(v3.z, s) << 24);
            tp[99]     = q8(v0.w, s) | (q8(v1.w, s) << 8) | (q8(v2.w, s) << 16) | (q8(v3.w, s) << 24);
        }
        __syncthreads();
        int* dst = (int*)(qx + (size_t)bh * ROWB);
        #pragma unroll
        for (int i = 0; i < 8; ++i) {                 // 1856 dwords
            int d = threadIdx.x + i * 256;
            if (d < ROWB / 4) {
                int u = d >> 2, dw = d & 3;
                int c = u / NSLOT, s2 = u - c * NSLOT;
                int v = 0;
                if (s2 >= 1 && s2 <= WW)
                    v = tile32[(s2 - 1) * 33 + c * 4 + dw];
                dst[d] = v;
            }
        }
    } else if (blockIdx.x < NBLK_QX + NBLK_QW) {
        int d = (blockIdx.x - NBLK_QX) * 256 + threadIdx.x;  // 73728 dwords
        int g  = d / 18432;
        int r1 = d - g * 18432;
        int k  = r1 >> 9;
        int q9 = r1 & 511;
        int mi = q9 >> 8;
        int u2 = q9 & 255;
        int jh = u2 >> 7;
        int co31 = (u2 >> 2) & 31;
        int jl4  = u2 & 3;
        int co = g * 64 + mi * 32 + co31;
        int t = k >> 2, cc = k & 3;
        int kh = t / 3, kw = t - kh * 3;
        float s = __uint_as_float(mbits[1]) / QDIV;
        int pack = 0;
        #pragma unroll
        for (int j = 0; j < 4; ++j) {
            int ci = cc * 32 + jh * 16 + jl4 * 4 + j;
            float v = w[(((size_t)co * CIN + ci) * 3 + kh) * 3 + kw];
            pack |= q8(v, s) << (8 * j);
        }
        qw[d] = pack;
    } else {
        // zero-row block: clear the shared border row (464 x 16B)
        for (int d = threadIdx.x; d < ROWB / 16; d += 256)
            ((int4*)qxzero)[d] = int4{0, 0, 0, 0};
    }
}

// ---------- conv: i8-MFMA, 3 blocks/CU, fine-grained weight dbuf (r9 exact) ----------
// Block: 256 thr / 4 waves; 64 co (group g) x 4 output rows; wave = 64co x 56px,
// acc[2][2]. LDS: x rows h0-1..h0+4 (44.5 KB) + weight dbuf 2x4KB = 52.7 KB
// -> 3 blocks/CU (12 waves, 3/SIMD). K-loop: 18 segments x 2 chunks of pure
// ds_read+MFMA; 1 staging load/thread/segment; __syncthreads per segment —
// compiler free to pipeline ds_reads across the segment.
__global__ __launch_bounds__(256, 3) void conv_mfma_kernel(
        const signed char* __restrict__ qxz,   // [zero row | qx rows]
        const signed char* __restrict__ qw3,
        const unsigned* __restrict__ mbits,
        const float* __restrict__ bias,
        float* __restrict__ out) {
    __shared__ signed char lds[LDS_TOTAL];
    signed char* xlds = lds;
    signed char* wlds = lds + XLDS;

    // XCD-chunked swizzle (1792 % 8 == 0 -> bijective); g fastest in a chunk
    const int sbid = (blockIdx.x & 7) * 224 + (blockIdx.x >> 3);
    const int g    = sbid & 3;
    const int brg  = sbid >> 2;       // 0..447
    const int rg   = brg % 14;
    const int b    = brg / 14;
    const int h0   = rg * 4;

    const int tid    = threadIdx.x;
    const int rowidx = tid >> 6;      // wave id = output row 0..3
    const int lane   = tid & 63;
    const int l31    = tid & 31;
    const int lhalf  = (tid >> 5) & 1;

    const signed char* wgrp = qw3 + (size_t)g * WGRP;

    // ---- prologue: weight segment 0 + x rows h0-1..h0+4 (2784 16B units) ----
    load_lds16(wgrp + tid * 16, wlds + tid * 16);
    #pragma unroll
    for (int i = 0; i < 11; ++i) {
        const int u = tid + i * 256;
        if (u < 2784) {
            const int r = u / 464, c = u - r * 464;
            const int hy = h0 - 1 + r;
            const signed char* src = (hy >= 0 && hy < HH)
                ? qxz + (size_t)(1 + b * HH + hy) * ROWB + c * 16
                : qxz + c * 16;
            load_lds16(src, xlds + u * 16);
        }
    }
    __syncthreads();

    v16i acc[2][2];
    #pragma unroll
    for (int mi = 0; mi < 2; ++mi)
        #pragma unroll
        for (int ni = 0; ni < 2; ++ni)
            #pragma unroll
            for (int r = 0; r < 16; ++r) acc[mi][ni][r] = 0;

    #pragma unroll
    for (int s = 0; s < 18; ++s) {
        if (s < 17)   // stage next 2-chunk segment: one 16B load per thread
            load_lds16(wgrp + (s + 1) * WSEG + tid * 16,
                       wlds + ((s + 1) & 1) * WSEG + tid * 16);

        const signed char* wseg = wlds + (s & 1) * WSEG + lane * 16;
        #pragma unroll
        for (int j = 0; j < 2; ++j) {
            const int K = s * 2 + j;
            const int t = K >> 2, cc = K & 3;
            const int kh = t / 3, kw = t - kh * 3;
            const v4i a0 = *(const v4i*)(wseg + j * 2048);
            const v4i a1 = *(const v4i*)(wseg + j * 2048 + 1024);
            const signed char* xp = xlds + (rowidx + kh) * ROWB
                                    + (cc * 2 + lhalf) * CSTRIDE + (l31 + kw) * 16;
            const v4i b0 = *(const v4i*)xp;
            const v4i b1 = *(const v4i*)(xp + 512);
            acc[0][0] = __builtin_amdgcn_mfma_i32_32x32x32_i8(a0, b0, acc[0][0], 0, 0, 0);
            acc[1][0] = __builtin_amdgcn_mfma_i32_32x32x32_i8(a1, b0, acc[1][0], 0, 0, 0);
            acc[0][1] = __builtin_amdgcn_mfma_i32_32x32x32_i8(a0, b1, acc[0][1], 0, 0, 0);
            acc[1][1] = __builtin_amdgcn_mfma_i32_32x32x32_i8(a1, b1, acc[1][1], 0, 0, 0);
        }
        if (s < 17) __syncthreads();   // publish next buffer; overlaps across 3 blocks/CU
    }

    // ---- epilogue: dequant + bias ----
    const float s = (__uint_as_float(mbits[0]) / QDIV) *
                    (__uint_as_float(mbits[1]) / QDIV);
    const int hrow = h0 + rowidx;
    #pragma unroll
    for (int mi = 0; mi < 2; ++mi) {
        #pragma unroll
        for (int r = 0; r < 16; ++r) {
            const int co = g * 64 + mi * 32 + (r & 3) + 8 * (r >> 2) + 4 * lhalf;
            const float bv = bias[co];
            float* orow = out + ((size_t)(b * COUT + co) * HH + hrow) * WW;
            orow[l31] = (float)acc[mi][0][r] * s + bv;
            if (l31 < WW - 32) orow[32 + l31] = (float)acc[mi][1][r] * s + bv;
        }
    }
}

extern "C" void kernel_launch(void* const* d_in, const int* in_sizes, int n_in,
                              void* d_out, int out_size, void* d_ws, size_t ws_size,
                              hipStream_t stream) {
    const float* x    = (const float*)d_in[0];
    const float* w    = (const float*)d_in[1];
    const float* bias = (const float*)d_in[2];
    float* out = (float*)d_out;

    unsigned* mbits = (unsigned*)d_ws;
    signed char* qxz = (signed char*)d_ws + 256;     // [zero row | qx rows]
    signed char* qx  = qxz + ROWB;
    signed char* qw3 = qx + (size_t)B_ * HH * ROWB;

    hipMemsetAsync(d_ws, 0, 8, stream);              // mbits only
    hipLaunchKernelGGL(absmax_all_kernel, dim3(NBLK_AX + NBLK_AW), dim3(256), 0, stream,
                       x, w, mbits);
    hipLaunchKernelGGL(quant_all_kernel, dim3(NBLK_QX + NBLK_QW + 1), dim3(256), 0, stream,
                       x, w, qx, (int*)qw3, qxz, mbits);
    hipLaunchKernelGGL(conv_mfma_kernel, dim3(B_ * 14 * 4), dim3(256), 0, stream,
                       qxz, qw3, mbits, bias, out);
}